// Round 1
// baseline (1011.468 us; speedup 1.0000x reference)
//
#include <hip/hip_runtime.h>
#include <hip/hip_bf16.h>

#define NN 20000
#define NEDGE 200000
#define NG 500
#define KTOP 30
#define HDIM 512

// ---------------- setup kernels ----------------

__global__ void k_init(int* indeg, int* ccur, int* gcnt) {
    int i = blockIdx.x * 256 + threadIdx.x;
    if (i < NN) { indeg[i] = 0; ccur[i] = 0; }
    if (i < NG) gcnt[i] = 0;
}

__global__ void k_count(const int* __restrict__ dst, int* indeg, int ne) {
    int e = blockIdx.x * 256 + threadIdx.x;
    if (e < ne) atomicAdd(&indeg[dst[e]], 1);
}

__global__ void k_gcount(const int* __restrict__ batch, int* gcnt) {
    int i = blockIdx.x * 256 + threadIdx.x;
    if (i < NN) atomicAdd(&gcnt[batch[i]], 1);
}

__global__ void k_dinv(const int* __restrict__ indeg, float* dinv) {
    int i = blockIdx.x * 256 + threadIdx.x;
    if (i < NN) dinv[i] = rsqrtf((float)(indeg[i] + 1));
}

// single-block exclusive scan; out has n+1 entries
__global__ void k_scan(const int* __restrict__ in, int* __restrict__ out, int n) {
    const int NT = 256;
    __shared__ int sums[NT];
    int t = threadIdx.x;
    int per = (n + NT - 1) / NT;
    int s0 = t * per;
    int local = 0;
    for (int k = 0; k < per; ++k) { int idx = s0 + k; if (idx < n) local += in[idx]; }
    sums[t] = local;
    __syncthreads();
    for (int off = 1; off < NT; off <<= 1) {
        int v = (t >= off) ? sums[t - off] : 0;
        __syncthreads();
        sums[t] += v;
        __syncthreads();
    }
    int run = sums[t] - local;  // exclusive prefix
    for (int k = 0; k < per; ++k) { int idx = s0 + k; if (idx < n) { out[idx] = run; run += in[idx]; } }
    if (t == NT - 1) out[n] = run;
}

__global__ void k_fill(const int* __restrict__ src, const int* __restrict__ dst,
                       const int* __restrict__ cstart, int* ccur, int* csrc, int ne) {
    int e = blockIdx.x * 256 + threadIdx.x;
    if (e < ne) {
        int d = dst[e];
        int pos = cstart[d] + atomicAdd(&ccur[d], 1);
        csrc[pos] = src[e];
    }
}

// ---------------- GEMM: C(M x 512) = A(M x 512) @ B(512 x 512) ----------------
// 128x128 block tile, 256 threads, 8x8 micro-tile, BK=8

__global__ __launch_bounds__(256) void k_gemm(const float* __restrict__ A, const float* __restrict__ B,
                                              float* __restrict__ C, int M) {
    const int K = 512, N = 512;
    __shared__ float As[8][128];
    __shared__ float Bs[8][128];
    int t = threadIdx.x;
    int bm = blockIdx.x * 128, bn = blockIdx.y * 128;
    int tm = t >> 4, tn = t & 15;
    float acc[8][8];
    #pragma unroll
    for (int i = 0; i < 8; ++i)
        #pragma unroll
        for (int j = 0; j < 8; ++j) acc[i][j] = 0.f;

    int arow = t >> 1, acol = (t & 1) * 4;
    int brow = t >> 5, bcol = (t & 31) * 4;
    int arow_c = min(bm + arow, M - 1);
    const float* Aptr = A + (size_t)arow_c * K + acol;
    const float* Bptr = B + (size_t)brow * N + bn + bcol;

    for (int k0 = 0; k0 < K; k0 += 8) {
        float4 av = *(const float4*)(Aptr + k0);
        float4 bv = *(const float4*)(Bptr + (size_t)k0 * N);
        As[acol + 0][arow] = av.x;
        As[acol + 1][arow] = av.y;
        As[acol + 2][arow] = av.z;
        As[acol + 3][arow] = av.w;
        *(float4*)&Bs[brow][bcol] = bv;
        __syncthreads();
        #pragma unroll
        for (int kk = 0; kk < 8; ++kk) {
            float a[8], b[8];
            #pragma unroll
            for (int i = 0; i < 8; ++i) a[i] = As[kk][tm * 8 + i];
            #pragma unroll
            for (int j = 0; j < 8; ++j) b[j] = Bs[kk][tn * 8 + j];
            #pragma unroll
            for (int i = 0; i < 8; ++i)
                #pragma unroll
                for (int j = 0; j < 8; ++j)
                    acc[i][j] = fmaf(a[i], b[j], acc[i][j]);
        }
        __syncthreads();
    }
    #pragma unroll
    for (int i = 0; i < 8; ++i) {
        int r = bm + tm * 8 + i;
        if (r < M) {
            float4 v0 = make_float4(acc[i][0], acc[i][1], acc[i][2], acc[i][3]);
            float4 v1 = make_float4(acc[i][4], acc[i][5], acc[i][6], acc[i][7]);
            *(float4*)(C + (size_t)r * N + bn + tn * 8)     = v0;
            *(float4*)(C + (size_t)r * N + bn + tn * 8 + 4) = v1;
        }
    }
}

// ---------------- aggregation: one wave per node ----------------
// out[i] = elu( sum_{s in N(i)} h[s]*dinv[s]*dinv[i] + h[i]*dinv[i]^2 + bias (+ res[i]) )

__global__ __launch_bounds__(256) void k_agg(const float* __restrict__ h, const int* __restrict__ cstart,
                                             const int* __restrict__ csrc, const float* __restrict__ dinv,
                                             const float* __restrict__ bias, const float* __restrict__ res,
                                             float* __restrict__ out) {
    int w = blockIdx.x * 4 + (threadIdx.x >> 6);
    if (w >= NN) return;
    int lane = threadIdx.x & 63;
    float di = dinv[w];
    float acc[8] = {0, 0, 0, 0, 0, 0, 0, 0};
    int e0 = cstart[w], e1 = cstart[w + 1];
    for (int j = e0; j < e1; ++j) {
        int s = csrc[j];
        float wt = dinv[s] * di;
        const float* hr = h + (size_t)s * HDIM + lane * 8;
        float4 v0 = *(const float4*)hr;
        float4 v1 = *(const float4*)(hr + 4);
        acc[0] = fmaf(v0.x, wt, acc[0]); acc[1] = fmaf(v0.y, wt, acc[1]);
        acc[2] = fmaf(v0.z, wt, acc[2]); acc[3] = fmaf(v0.w, wt, acc[3]);
        acc[4] = fmaf(v1.x, wt, acc[4]); acc[5] = fmaf(v1.y, wt, acc[5]);
        acc[6] = fmaf(v1.z, wt, acc[6]); acc[7] = fmaf(v1.w, wt, acc[7]);
    }
    {
        float wt = di * di;
        const float* hr = h + (size_t)w * HDIM + lane * 8;
        float4 v0 = *(const float4*)hr;
        float4 v1 = *(const float4*)(hr + 4);
        acc[0] = fmaf(v0.x, wt, acc[0]); acc[1] = fmaf(v0.y, wt, acc[1]);
        acc[2] = fmaf(v0.z, wt, acc[2]); acc[3] = fmaf(v0.w, wt, acc[3]);
        acc[4] = fmaf(v1.x, wt, acc[4]); acc[5] = fmaf(v1.y, wt, acc[5]);
        acc[6] = fmaf(v1.z, wt, acc[6]); acc[7] = fmaf(v1.w, wt, acc[7]);
    }
    const float* bptr = bias + lane * 8;
    const float* rptr = res ? res + (size_t)w * HDIM + lane * 8 : nullptr;
    float v[8];
    #pragma unroll
    for (int q = 0; q < 8; ++q) {
        float t = acc[q] + bptr[q];
        if (rptr) t += rptr[q];
        v[q] = t > 0.f ? t : (expf(t) - 1.f);
    }
    float* orow = out + (size_t)w * HDIM + lane * 8;
    *(float4*)orow       = make_float4(v[0], v[1], v[2], v[3]);
    *(float4*)(orow + 4) = make_float4(v[4], v[5], v[6], v[7]);
}

// ---------------- layer 3: h3 = x2 @ W3 (512 -> 1), wave per node ----------------

__global__ __launch_bounds__(256) void k_gemv3(const float* __restrict__ x2, const float* __restrict__ W3,
                                               float* __restrict__ h3) {
    int w = blockIdx.x * 4 + (threadIdx.x >> 6);
    if (w >= NN) return;
    int lane = threadIdx.x & 63;
    const float* r = x2 + (size_t)w * HDIM + lane * 8;
    const float* wp = W3 + lane * 8;
    float4 a0 = *(const float4*)r, a1 = *(const float4*)(r + 4);
    float4 w0 = *(const float4*)wp, w1 = *(const float4*)(wp + 4);
    float acc = a0.x * w0.x + a0.y * w0.y + a0.z * w0.z + a0.w * w0.w
              + a1.x * w1.x + a1.y * w1.y + a1.z * w1.z + a1.w * w1.w;
    #pragma unroll
    for (int off = 32; off; off >>= 1) acc += __shfl_down(acc, off);
    if (lane == 0) h3[w] = acc;
}

__global__ void k_agg3(const float* __restrict__ h3, const int* __restrict__ cstart,
                       const int* __restrict__ csrc, const float* __restrict__ dinv,
                       const float* __restrict__ b3, float* __restrict__ key) {
    int i = blockIdx.x * 256 + threadIdx.x;
    if (i >= NN) return;
    float di = dinv[i];
    float acc = h3[i] * di * di;
    int e0 = cstart[i], e1 = cstart[i + 1];
    for (int j = e0; j < e1; ++j) {
        int s = csrc[j];
        acc = fmaf(h3[s], dinv[s] * di, acc);
    }
    key[i] = acc + b3[0];
}

// ---------------- sort-pool: per-graph stable descending rank, keep top-30 indices ----------------

#define MAXN 2048
__global__ __launch_bounds__(256) void k_select(const float* __restrict__ key, const int* __restrict__ gstart,
                                                int* __restrict__ sel) {
    int g = blockIdx.x;
    int s = gstart[g], e = gstart[g + 1];
    int cnt = e - s;
    if (cnt > MAXN) cnt = MAXN;
    __shared__ float ks[MAXN];
    __shared__ int sels[KTOP];
    for (int i = threadIdx.x; i < cnt; i += 256) ks[i] = key[s + i];
    if (threadIdx.x < KTOP) sels[threadIdx.x] = -1;
    __syncthreads();
    for (int i = threadIdx.x; i < cnt; i += 256) {
        float ki = ks[i];
        int r = 0;
        for (int j = 0; j < cnt; ++j) {
            float kj = ks[j];
            r += (kj > ki) || (kj == ki && j < i);
        }
        if (r < KTOP) sels[r] = s + i;
    }
    __syncthreads();
    if (threadIdx.x < KTOP) sel[g * KTOP + threadIdx.x] = sels[threadIdx.x];
}

// ---------------- conv1 (kernel width 1025, stride 1025) + relu ----------------
// c1[g][oc][p] = relu( dot(feat_row(sel[g][p]), cw1[oc]) + cb1[oc] ), feat = [x1, x2, key]

__global__ __launch_bounds__(256) void k_conv1(const float* __restrict__ x1, const float* __restrict__ x2,
                                               const float* __restrict__ key, const int* __restrict__ sel,
                                               const float* __restrict__ cw1, const float* __restrict__ cb1,
                                               float* __restrict__ c1) {
    int g = blockIdx.x, t = threadIdx.x;
    __shared__ float f[1025];
    __shared__ float red[16][17];
    int oc = t >> 4, ch = t & 15;
    for (int p = 0; p < KTOP; ++p) {
        int node = sel[g * KTOP + p];
        __syncthreads();  // protect f/red from previous iteration
        if (node >= 0) {
            f[t]       = x1[(size_t)node * HDIM + t];
            f[t + 256] = x1[(size_t)node * HDIM + t + 256];
            f[512 + t] = x2[(size_t)node * HDIM + t];
            f[768 + t] = x2[(size_t)node * HDIM + t + 256];
            if (t == 0) f[1024] = key[node];
        } else {
            f[t] = 0.f; f[t + 256] = 0.f; f[512 + t] = 0.f; f[768 + t] = 0.f;
            if (t == 0) f[1024] = 0.f;
        }
        __syncthreads();
        float pd = 0.f;
        int k0 = ch * 65, k1 = min(1025, k0 + 65);
        const float* wrow = cw1 + (size_t)oc * 1025;
        for (int k = k0; k < k1; ++k) pd = fmaf(f[k], wrow[k], pd);
        red[oc][ch] = pd;
        __syncthreads();
        if (t < 16) {
            float ssum = cb1[t];
            #pragma unroll
            for (int c = 0; c < 16; ++c) ssum += red[t][c];
            c1[((size_t)g * 16 + t) * KTOP + p] = fmaxf(ssum, 0.f);
        }
    }
}

// ---------------- maxpool(2) + conv2 (16->32, width 5) + relu ----------------

__global__ __launch_bounds__(384) void k_conv2(const float* __restrict__ c1, const float* __restrict__ cw2,
                                               const float* __restrict__ cb2, float* __restrict__ z2) {
    int g = blockIdx.x, t = threadIdx.x;
    __shared__ float m[16][15];
    if (t < 240) {
        int ic = t / 15, q = t % 15;
        const float* row = c1 + ((size_t)g * 16 + ic) * KTOP;
        m[ic][q] = fmaxf(row[2 * q], row[2 * q + 1]);
    }
    __syncthreads();
    if (t < 352) {
        int oc = t / 11, tt = t % 11;
        float acc = cb2[oc];
        #pragma unroll
        for (int ic = 0; ic < 16; ++ic)
            #pragma unroll
            for (int j = 0; j < 5; ++j)
                acc = fmaf(m[ic][tt + j], cw2[((size_t)oc * 16 + ic) * 5 + j], acc);
        z2[(size_t)g * 352 + t] = fmaxf(acc, 0.f);
    }
}

// ---------------- fc1 (352->512) + relu + fc2 (512->10) ----------------

__global__ __launch_bounds__(256) void k_fc(const float* __restrict__ z2, const float* __restrict__ lw1,
                                            const float* __restrict__ lb1, const float* __restrict__ lw2,
                                            const float* __restrict__ lb2, float* __restrict__ outp) {
    int g = blockIdx.x, t = threadIdx.x;
    __shared__ float zr[352];
    __shared__ float z3[512];
    if (t < 176) { zr[t] = z2[(size_t)g * 352 + t]; zr[t + 176] = z2[(size_t)g * 352 + t + 176]; }
    __syncthreads();
    #pragma unroll
    for (int nb = 0; nb < 2; ++nb) {
        int nn = t + nb * 256;
        float acc = lb1[nn];
        for (int k = 0; k < 352; ++k) acc = fmaf(zr[k], lw1[(size_t)k * 512 + nn], acc);
        z3[nn] = fmaxf(acc, 0.f);
    }
    __syncthreads();
    if (t < 160) {
        int oc = t >> 4, l = t & 15;
        float acc = 0.f;
        for (int k = l; k < 512; k += 16) acc = fmaf(z3[k], lw2[(size_t)k * 10 + oc], acc);
        #pragma unroll
        for (int off = 1; off < 16; off <<= 1) acc += __shfl_xor(acc, off);
        if (l == 0) outp[g * 10 + oc] = acc + lb2[oc];
    }
}

// ---------------- launch ----------------

extern "C" void kernel_launch(void* const* d_in, const int* in_sizes, int n_in,
                              void* d_out, int out_size, void* d_ws, size_t ws_size,
                              hipStream_t stream) {
    const float* x    = (const float*)d_in[0];
    const int*   ei   = (const int*)d_in[1];
    const int*   batch= (const int*)d_in[2];
    const float* W1   = (const float*)d_in[3];
    const float* b1   = (const float*)d_in[4];
    const float* W2   = (const float*)d_in[5];
    const float* b2   = (const float*)d_in[6];
    const float* W3   = (const float*)d_in[7];
    const float* b3   = (const float*)d_in[8];
    const float* cw1  = (const float*)d_in[9];
    const float* cb1  = (const float*)d_in[10];
    const float* cw2  = (const float*)d_in[11];
    const float* cb2  = (const float*)d_in[12];
    const float* lw1  = (const float*)d_in[13];
    const float* lb1  = (const float*)d_in[14];
    const float* lw2  = (const float*)d_in[15];
    const float* lb2  = (const float*)d_in[16];

    const int NE = in_sizes[1] / 2;
    const int* srcp = ei;
    const int* dstp = ei + NE;

    char* ws = (char*)d_ws;
    size_t o = 0;
    auto al = [&](size_t b) { size_t r = o; o += (b + 255) & ~(size_t)255; return r; };
    int*   indeg  = (int*)(ws + al((size_t)NN * 4));
    int*   ccur   = (int*)(ws + al((size_t)NN * 4));
    int*   cstart = (int*)(ws + al((size_t)(NN + 1) * 4));
    int*   csrc   = (int*)(ws + al((size_t)NE * 4));
    float* dinv   = (float*)(ws + al((size_t)NN * 4));
    float* h      = (float*)(ws + al((size_t)NN * HDIM * 4));
    float* x1     = (float*)(ws + al((size_t)NN * HDIM * 4));
    float* x2     = (float*)(ws + al((size_t)NN * HDIM * 4));
    float* h3     = (float*)(ws + al((size_t)NN * 4));
    float* key    = (float*)(ws + al((size_t)NN * 4));
    int*   gcnt   = (int*)(ws + al((size_t)NG * 4));
    int*   gstart = (int*)(ws + al((size_t)(NG + 1) * 4));
    int*   sel    = (int*)(ws + al((size_t)NG * KTOP * 4));
    float* c1     = (float*)(ws + al((size_t)NG * 16 * KTOP * 4));
    float* z2     = (float*)(ws + al((size_t)NG * 352 * 4));
    (void)ws_size; (void)n_in; (void)out_size;

    int nb_n = (NN + 255) / 256;       // 79
    int nb_e = (NE + 255) / 256;

    k_init<<<nb_n, 256, 0, stream>>>(indeg, ccur, gcnt);
    k_count<<<nb_e, 256, 0, stream>>>(dstp, indeg, NE);
    k_gcount<<<nb_n, 256, 0, stream>>>(batch, gcnt);
    k_dinv<<<nb_n, 256, 0, stream>>>(indeg, dinv);
    k_scan<<<1, 256, 0, stream>>>(indeg, cstart, NN);
    k_scan<<<1, 256, 0, stream>>>(gcnt, gstart, NG);
    k_fill<<<nb_e, 256, 0, stream>>>(srcp, dstp, cstart, ccur, csrc, NE);

    dim3 gg((NN + 127) / 128, 4);
    k_gemm<<<gg, 256, 0, stream>>>(x, W1, h, NN);
    k_agg<<<NN / 4, 256, 0, stream>>>(h, cstart, csrc, dinv, b1, nullptr, x1);
    k_gemm<<<gg, 256, 0, stream>>>(x1, W2, h, NN);
    k_agg<<<NN / 4, 256, 0, stream>>>(h, cstart, csrc, dinv, b2, x1, x2);
    k_gemv3<<<NN / 4, 256, 0, stream>>>(x2, W3, h3);
    k_agg3<<<nb_n, 256, 0, stream>>>(h3, cstart, csrc, dinv, b3, key);

    k_select<<<NG, 256, 0, stream>>>(key, gstart, sel);
    k_conv1<<<NG, 256, 0, stream>>>(x1, x2, key, sel, cw1, cb1, c1);
    k_conv2<<<NG, 384, 0, stream>>>(c1, cw2, cb2, z2);
    k_fc<<<NG, 256, 0, stream>>>(z2, lw1, lb1, lw2, lb2, (float*)d_out);
}

// Round 6
// 746.529 us; speedup vs baseline: 1.3549x; 1.3549x over previous
//
#include <hip/hip_runtime.h>
#include <hip/hip_bf16.h>

#define NN 20000
#define NEDGE 200000
#define NG 500
#define KTOP 30
#define HDIM 512

// ---------------- setup kernels ----------------

__global__ void k_init(int* indeg, int* ccur, int* gcnt) {
    int i = blockIdx.x * 256 + threadIdx.x;
    if (i < NN) { indeg[i] = 0; ccur[i] = 0; }
    if (i < NG) gcnt[i] = 0;
}

__global__ void k_count(const int* __restrict__ dst, int* indeg, int ne) {
    int e = blockIdx.x * 256 + threadIdx.x;
    if (e < ne) atomicAdd(&indeg[dst[e]], 1);
}

__global__ void k_gcount(const int* __restrict__ batch, int* gcnt) {
    int i = blockIdx.x * 256 + threadIdx.x;
    if (i < NN) atomicAdd(&gcnt[batch[i]], 1);
}

__global__ void k_dinv(const int* __restrict__ indeg, float* dinv) {
    int i = blockIdx.x * 256 + threadIdx.x;
    if (i < NN) dinv[i] = rsqrtf((float)(indeg[i] + 1));
}

// single-block exclusive scan; out has n+1 entries
__global__ void k_scan(const int* __restrict__ in, int* __restrict__ out, int n) {
    const int NT = 256;
    __shared__ int sums[NT];
    int t = threadIdx.x;
    int per = (n + NT - 1) / NT;
    int s0 = t * per;
    int local = 0;
    for (int k = 0; k < per; ++k) { int idx = s0 + k; if (idx < n) local += in[idx]; }
    sums[t] = local;
    __syncthreads();
    for (int off = 1; off < NT; off <<= 1) {
        int v = (t >= off) ? sums[t - off] : 0;
        __syncthreads();
        sums[t] += v;
        __syncthreads();
    }
    int run = sums[t] - local;  // exclusive prefix
    for (int k = 0; k < per; ++k) { int idx = s0 + k; if (idx < n) { out[idx] = run; run += in[idx]; } }
    if (t == NT - 1) out[n] = run;
}

__global__ void k_fill(const int* __restrict__ src, const int* __restrict__ dst,
                       const int* __restrict__ cstart, int* ccur, int* csrc, int ne) {
    int e = blockIdx.x * 256 + threadIdx.x;
    if (e < ne) {
        int d = dst[e];
        int pos = cstart[d] + atomicAdd(&ccur[d], 1);
        csrc[pos] = src[e];
    }
}

// ---------------- GEMM: C(M x 512) = A(M x 512) @ B(512 x 512) ----------------
// 128x128 block tile, 256 threads, 8x8 micro-tile, BK=8
// Register-prefetch pipeline: next k-tile loaded into regs during compute.
// Accumulation order identical to the non-pipelined version (numerics unchanged).

__global__ __launch_bounds__(256) void k_gemm(const float* __restrict__ A, const float* __restrict__ B,
                                              float* __restrict__ C, int M) {
    const int K = 512, N = 512;
    __shared__ float As[8][128];
    __shared__ float Bs[8][128];
    int t = threadIdx.x;
    int bm = blockIdx.x * 128, bn = blockIdx.y * 128;
    int tm = t >> 4, tn = t & 15;
    float acc[8][8];
    #pragma unroll
    for (int i = 0; i < 8; ++i)
        #pragma unroll
        for (int j = 0; j < 8; ++j) acc[i][j] = 0.f;

    int arow = t >> 1, acol = (t & 1) * 4;
    int brow = t >> 5, bcol = (t & 31) * 4;
    int arow_c = min(bm + arow, M - 1);
    const float* Aptr = A + (size_t)arow_c * K + acol;
    const float* Bptr = B + (size_t)brow * N + bn + bcol;

    float4 av = *(const float4*)(Aptr);
    float4 bv = *(const float4*)(Bptr);

    for (int k0 = 0; k0 < K; k0 += 8) {
        As[acol + 0][arow] = av.x;
        As[acol + 1][arow] = av.y;
        As[acol + 2][arow] = av.z;
        As[acol + 3][arow] = av.w;
        *(float4*)&Bs[brow][bcol] = bv;
        __syncthreads();
        if (k0 + 8 < K) {
            av = *(const float4*)(Aptr + k0 + 8);
            bv = *(const float4*)(Bptr + (size_t)(k0 + 8) * N);
        }
        #pragma unroll
        for (int kk = 0; kk < 8; ++kk) {
            float a[8], b[8];
            #pragma unroll
            for (int i = 0; i < 8; ++i) a[i] = As[kk][tm * 8 + i];
            #pragma unroll
            for (int j = 0; j < 8; ++j) b[j] = Bs[kk][tn * 8 + j];
            #pragma unroll
            for (int i = 0; i < 8; ++i)
                #pragma unroll
                for (int j = 0; j < 8; ++j)
                    acc[i][j] = fmaf(a[i], b[j], acc[i][j]);
        }
        __syncthreads();
    }
    #pragma unroll
    for (int i = 0; i < 8; ++i) {
        int r = bm + tm * 8 + i;
        if (r < M) {
            float4 v0 = make_float4(acc[i][0], acc[i][1], acc[i][2], acc[i][3]);
            float4 v1 = make_float4(acc[i][4], acc[i][5], acc[i][6], acc[i][7]);
            *(float4*)(C + (size_t)r * N + bn + tn * 8)     = v0;
            *(float4*)(C + (size_t)r * N + bn + tn * 8 + 4) = v1;
        }
    }
}

// ---------------- aggregation: one wave per node ----------------

__global__ __launch_bounds__(256) void k_agg(const float* __restrict__ h, const int* __restrict__ cstart,
                                             const int* __restrict__ csrc, const float* __restrict__ dinv,
                                             const float* __restrict__ bias, const float* __restrict__ res,
                                             float* __restrict__ out) {
    int w = blockIdx.x * 4 + (threadIdx.x >> 6);
    if (w >= NN) return;
    int lane = threadIdx.x & 63;
    float di = dinv[w];
    float acc[8] = {0, 0, 0, 0, 0, 0, 0, 0};
    int e0 = cstart[w], e1 = cstart[w + 1];
    for (int j = e0; j < e1; ++j) {
        int s = csrc[j];
        float wt = dinv[s] * di;
        const float* hr = h + (size_t)s * HDIM + lane * 8;
        float4 v0 = *(const float4*)hr;
        float4 v1 = *(const float4*)(hr + 4);
        acc[0] = fmaf(v0.x, wt, acc[0]); acc[1] = fmaf(v0.y, wt, acc[1]);
        acc[2] = fmaf(v0.z, wt, acc[2]); acc[3] = fmaf(v0.w, wt, acc[3]);
        acc[4] = fmaf(v1.x, wt, acc[4]); acc[5] = fmaf(v1.y, wt, acc[5]);
        acc[6] = fmaf(v1.z, wt, acc[6]); acc[7] = fmaf(v1.w, wt, acc[7]);
    }
    {
        float wt = di * di;
        const float* hr = h + (size_t)w * HDIM + lane * 8;
        float4 v0 = *(const float4*)hr;
        float4 v1 = *(const float4*)(hr + 4);
        acc[0] = fmaf(v0.x, wt, acc[0]); acc[1] = fmaf(v0.y, wt, acc[1]);
        acc[2] = fmaf(v0.z, wt, acc[2]); acc[3] = fmaf(v0.w, wt, acc[3]);
        acc[4] = fmaf(v1.x, wt, acc[4]); acc[5] = fmaf(v1.y, wt, acc[5]);
        acc[6] = fmaf(v1.z, wt, acc[6]); acc[7] = fmaf(v1.w, wt, acc[7]);
    }
    const float* bptr = bias + lane * 8;
    const float* rptr = res ? res + (size_t)w * HDIM + lane * 8 : nullptr;
    float v[8];
    #pragma unroll
    for (int q = 0; q < 8; ++q) {
        float t = acc[q] + bptr[q];
        if (rptr) t += rptr[q];
        v[q] = t > 0.f ? t : (expf(t) - 1.f);
    }
    float* orow = out + (size_t)w * HDIM + lane * 8;
    *(float4*)orow       = make_float4(v[0], v[1], v[2], v[3]);
    *(float4*)(orow + 4) = make_float4(v[4], v[5], v[6], v[7]);
}

// ---------------- layer 3: h3 = x2 @ W3 (512 -> 1), wave per node ----------------

__global__ __launch_bounds__(256) void k_gemv3(const float* __restrict__ x2, const float* __restrict__ W3,
                                               float* __restrict__ h3) {
    int w = blockIdx.x * 4 + (threadIdx.x >> 6);
    if (w >= NN) return;
    int lane = threadIdx.x & 63;
    const float* r = x2 + (size_t)w * HDIM + lane * 8;
    const float* wp = W3 + lane * 8;
    float4 a0 = *(const float4*)r, a1 = *(const float4*)(r + 4);
    float4 w0 = *(const float4*)wp, w1 = *(const float4*)(wp + 4);
    float acc = a0.x * w0.x + a0.y * w0.y + a0.z * w0.z + a0.w * w0.w
              + a1.x * w1.x + a1.y * w1.y + a1.z * w1.z + a1.w * w1.w;
    #pragma unroll
    for (int off = 32; off; off >>= 1) acc += __shfl_down(acc, off);
    if (lane == 0) h3[w] = acc;
}

__global__ void k_agg3(const float* __restrict__ h3, const int* __restrict__ cstart,
                       const int* __restrict__ csrc, const float* __restrict__ dinv,
                       const float* __restrict__ b3, float* __restrict__ key) {
    int i = blockIdx.x * 256 + threadIdx.x;
    if (i >= NN) return;
    float di = dinv[i];
    float acc = h3[i] * di * di;
    int e0 = cstart[i], e1 = cstart[i + 1];
    for (int j = e0; j < e1; ++j) {
        int s = csrc[j];
        acc = fmaf(h3[s], dinv[s] * di, acc);
    }
    key[i] = acc + b3[0];
}

// ---------------- sort-pool: per-graph stable descending rank, keep top-30 indices ----------------

#define MAXN 2048
__global__ __launch_bounds__(256) void k_select(const float* __restrict__ key, const int* __restrict__ gstart,
                                                int* __restrict__ sel) {
    int g = blockIdx.x;
    int s = gstart[g], e = gstart[g + 1];
    int cnt = e - s;
    if (cnt > MAXN) cnt = MAXN;
    __shared__ float ks[MAXN];
    __shared__ int sels[KTOP];
    for (int i = threadIdx.x; i < cnt; i += 256) ks[i] = key[s + i];
    if (threadIdx.x < KTOP) sels[threadIdx.x] = -1;
    __syncthreads();
    for (int i = threadIdx.x; i < cnt; i += 256) {
        float ki = ks[i];
        int r = 0;
        for (int j = 0; j < cnt; ++j) {
            float kj = ks[j];
            r += (kj > ki) || (kj == ki && j < i);
        }
        if (r < KTOP) sels[r] = s + i;
    }
    __syncthreads();
    if (threadIdx.x < KTOP) sel[g * KTOP + threadIdx.x] = sels[threadIdx.x];
}

// ---------------- conv1: one block per (graph, position) ----------------
// thread (oc,ch) walks k with stride 16 -> coalesced weight reads, broadcast LDS reads

__global__ __launch_bounds__(256) void k_conv1(const float* __restrict__ x1, const float* __restrict__ x2,
                                               const float* __restrict__ key, const int* __restrict__ sel,
                                               const float* __restrict__ cw1, const float* __restrict__ cb1,
                                               float* __restrict__ c1) {
    int gp = blockIdx.x;                 // g * KTOP + p
    int g = gp / KTOP, p = gp - g * KTOP;
    int t = threadIdx.x;
    int node = sel[gp];
    if (node < 0) {
        if (t < 16) c1[((size_t)g * 16 + t) * KTOP + p] = fmaxf(cb1[t], 0.f);
        return;
    }
    __shared__ float f[1025];
    __shared__ float red[16][17];
    if (t < 128) {
        ((float4*)f)[t] = ((const float4*)(x1 + (size_t)node * HDIM))[t];
    } else {
        ((float4*)(f + 512))[t - 128] = ((const float4*)(x2 + (size_t)node * HDIM))[t - 128];
    }
    if (t == 0) f[1024] = key[node];
    __syncthreads();
    int oc = t >> 4, ch = t & 15;
    const float* wrow = cw1 + (size_t)oc * 1025;
    float pd = 0.f;
    for (int k = ch; k < 1025; k += 16) pd = fmaf(f[k], wrow[k], pd);
    red[oc][ch] = pd;
    __syncthreads();
    if (t < 16) {
        float ssum = cb1[t];
        #pragma unroll
        for (int c = 0; c < 16; ++c) ssum += red[t][c];
        c1[((size_t)g * 16 + t) * KTOP + p] = fmaxf(ssum, 0.f);
    }
}

// ---------------- fused head: maxpool(2) + conv2 (16->32,w5) + relu + fc1 + relu + fc2 ----------------

__global__ __launch_bounds__(512) void k_head(const float* __restrict__ c1, const float* __restrict__ cw2,
                                              const float* __restrict__ cb2, const float* __restrict__ lw1,
                                              const float* __restrict__ lb1, const float* __restrict__ lw2,
                                              const float* __restrict__ lb2, float* __restrict__ outp) {
    int g = blockIdx.x, t = threadIdx.x;
    __shared__ float m[16][15];
    __shared__ float z2s[352];
    __shared__ float z3[512];
    if (t < 240) {
        int ic = t / 15, q = t % 15;
        const float* row = c1 + ((size_t)g * 16 + ic) * KTOP;
        m[ic][q] = fmaxf(row[2 * q], row[2 * q + 1]);
    }
    __syncthreads();
    if (t < 352) {
        int oc = t / 11, tt = t % 11;
        float acc = cb2[oc];
        #pragma unroll
        for (int ic = 0; ic < 16; ++ic)
            #pragma unroll
            for (int j = 0; j < 5; ++j)
                acc = fmaf(m[ic][tt + j], cw2[((size_t)oc * 16 + ic) * 5 + j], acc);
        z2s[t] = fmaxf(acc, 0.f);
    }
    __syncthreads();
    {
        float acc = lb1[t];
        for (int k = 0; k < 352; ++k) acc = fmaf(z2s[k], lw1[(size_t)k * 512 + t], acc);
        z3[t] = fmaxf(acc, 0.f);
    }
    __syncthreads();
    if (t < 160) {
        int oc = t >> 4, l = t & 15;
        float acc = 0.f;
        for (int k = l; k < 512; k += 16) acc = fmaf(z3[k], lw2[(size_t)k * 10 + oc], acc);
        #pragma unroll
        for (int off = 1; off < 16; off <<= 1) acc += __shfl_xor(acc, off);
        if (l == 0) outp[g * 10 + oc] = acc + lb2[oc];
    }
}

// ---------------- launch ----------------

extern "C" void kernel_launch(void* const* d_in, const int* in_sizes, int n_in,
                              void* d_out, int out_size, void* d_ws, size_t ws_size,
                              hipStream_t stream) {
    const float* x    = (const float*)d_in[0];
    const int*   ei   = (const int*)d_in[1];
    const int*   batch= (const int*)d_in[2];
    const float* W1   = (const float*)d_in[3];
    const float* b1   = (const float*)d_in[4];
    const float* W2   = (const float*)d_in[5];
    const float* b2   = (const float*)d_in[6];
    const float* W3   = (const float*)d_in[7];
    const float* b3   = (const float*)d_in[8];
    const float* cw1  = (const float*)d_in[9];
    const float* cb1  = (const float*)d_in[10];
    const float* cw2  = (const float*)d_in[11];
    const float* cb2  = (const float*)d_in[12];
    const float* lw1  = (const float*)d_in[13];
    const float* lb1  = (const float*)d_in[14];
    const float* lw2  = (const float*)d_in[15];
    const float* lb2  = (const float*)d_in[16];

    const int NE = in_sizes[1] / 2;
    const int* srcp = ei;
    const int* dstp = ei + NE;

    char* ws = (char*)d_ws;
    size_t o = 0;
    auto al = [&](size_t b) { size_t r = o; o += (b + 255) & ~(size_t)255; return r; };
    int*   indeg  = (int*)(ws + al((size_t)NN * 4));
    int*   ccur   = (int*)(ws + al((size_t)NN * 4));
    int*   cstart = (int*)(ws + al((size_t)(NN + 1) * 4));
    int*   csrc   = (int*)(ws + al((size_t)NE * 4));
    float* dinv   = (float*)(ws + al((size_t)NN * 4));
    float* h      = (float*)(ws + al((size_t)NN * HDIM * 4));
    float* x1     = (float*)(ws + al((size_t)NN * HDIM * 4));
    float* x2     = (float*)(ws + al((size_t)NN * HDIM * 4));
    float* h3     = (float*)(ws + al((size_t)NN * 4));
    float* key    = (float*)(ws + al((size_t)NN * 4));
    int*   gcnt   = (int*)(ws + al((size_t)NG * 4));
    int*   gstart = (int*)(ws + al((size_t)(NG + 1) * 4));
    int*   sel    = (int*)(ws + al((size_t)NG * KTOP * 4));
    float* c1     = (float*)(ws + al((size_t)NG * 16 * KTOP * 4));
    (void)ws_size; (void)n_in; (void)out_size;

    int nb_n = (NN + 255) / 256;
    int nb_e = (NE + 255) / 256;

    k_init<<<nb_n, 256, 0, stream>>>(indeg, ccur, gcnt);
    k_count<<<nb_e, 256, 0, stream>>>(dstp, indeg, NE);
    k_gcount<<<nb_n, 256, 0, stream>>>(batch, gcnt);
    k_dinv<<<nb_n, 256, 0, stream>>>(indeg, dinv);
    k_scan<<<1, 256, 0, stream>>>(indeg, cstart, NN);
    k_scan<<<1, 256, 0, stream>>>(gcnt, gstart, NG);
    k_fill<<<nb_e, 256, 0, stream>>>(srcp, dstp, cstart, ccur, csrc, NE);

    dim3 gg((NN + 127) / 128, 4);
    k_gemm<<<gg, 256, 0, stream>>>(x, W1, h, NN);
    k_agg<<<NN / 4, 256, 0, stream>>>(h, cstart, csrc, dinv, b1, nullptr, x1);
    k_gemm<<<gg, 256, 0, stream>>>(x1, W2, h, NN);
    k_agg<<<NN / 4, 256, 0, stream>>>(h, cstart, csrc, dinv, b2, x1, x2);
    k_gemv3<<<NN / 4, 256, 0, stream>>>(x2, W3, h3);
    k_agg3<<<nb_n, 256, 0, stream>>>(h3, cstart, csrc, dinv, b3, key);

    k_select<<<NG, 256, 0, stream>>>(key, gstart, sel);
    k_conv1<<<NG * KTOP, 256, 0, stream>>>(x1, x2, key, sel, cw1, cb1, c1);
    k_head<<<NG, 512, 0, stream>>>(c1, cw2, cb2, lw1, lb1, lw2, lb2, (float*)d_out);
}

// Round 7
// 683.985 us; speedup vs baseline: 1.4788x; 1.0914x over previous
//
#include <hip/hip_runtime.h>
#include <hip/hip_bf16.h>

#define NN 20000
#define NEDGE 200000
#define NG 500
#define KTOP 30
#define HDIM 512

typedef __attribute__((ext_vector_type(8))) short s16x8;
typedef __attribute__((ext_vector_type(4))) float f32x4;

__device__ __forceinline__ unsigned short f2bf(float f) {
    unsigned int u = __float_as_uint(f);
    return (unsigned short)((u + 0x7FFFu + ((u >> 16) & 1u)) >> 16);
}
__device__ __forceinline__ float bf2f(unsigned short s) {
    return __uint_as_float(((unsigned int)s) << 16);
}

// ---------------- setup kernels ----------------

__global__ void k_init(int* indeg, int* ccur, int* gcnt) {
    int i = blockIdx.x * 256 + threadIdx.x;
    if (i < NN) { indeg[i] = 0; ccur[i] = 0; }
    if (i < NG) gcnt[i] = 0;
}

__global__ void k_count(const int* __restrict__ dst, int* indeg, int ne) {
    int e = blockIdx.x * 256 + threadIdx.x;
    if (e < ne) atomicAdd(&indeg[dst[e]], 1);
}

__global__ void k_gcount(const int* __restrict__ batch, int* gcnt) {
    int i = blockIdx.x * 256 + threadIdx.x;
    if (i < NN) atomicAdd(&gcnt[batch[i]], 1);
}

__global__ void k_dinv(const int* __restrict__ indeg, float* dinv) {
    int i = blockIdx.x * 256 + threadIdx.x;
    if (i < NN) dinv[i] = rsqrtf((float)(indeg[i] + 1));
}

__global__ void k_scan(const int* __restrict__ in, int* __restrict__ out, int n) {
    const int NT = 256;
    __shared__ int sums[NT];
    int t = threadIdx.x;
    int per = (n + NT - 1) / NT;
    int s0 = t * per;
    int local = 0;
    for (int k = 0; k < per; ++k) { int idx = s0 + k; if (idx < n) local += in[idx]; }
    sums[t] = local;
    __syncthreads();
    for (int off = 1; off < NT; off <<= 1) {
        int v = (t >= off) ? sums[t - off] : 0;
        __syncthreads();
        sums[t] += v;
        __syncthreads();
    }
    int run = sums[t] - local;
    for (int k = 0; k < per; ++k) { int idx = s0 + k; if (idx < n) { out[idx] = run; run += in[idx]; } }
    if (t == NT - 1) out[n] = run;
}

__global__ void k_fill(const int* __restrict__ src, const int* __restrict__ dst,
                       const int* __restrict__ cstart, int* ccur, int* csrc, int ne) {
    int e = blockIdx.x * 256 + threadIdx.x;
    if (e < ne) {
        int d = dst[e];
        int pos = cstart[d] + atomicAdd(&ccur[d], 1);
        csrc[pos] = src[e];
    }
}

// ---------------- split passes: f32 -> 3x bf16 (hi/mid/lo) ----------------

__global__ __launch_bounds__(256) void k_split(const float* __restrict__ A,
                                               unsigned short* __restrict__ o0,
                                               unsigned short* __restrict__ o1,
                                               unsigned short* __restrict__ o2, int n4) {
    int i = blockIdx.x * 256 + threadIdx.x;
    if (i >= n4) return;
    float4 v = ((const float4*)A)[i];
    float f[4] = {v.x, v.y, v.z, v.w};
    unsigned short h0[4], h1[4], h2[4];
    #pragma unroll
    for (int j = 0; j < 4; ++j) {
        h0[j] = f2bf(f[j]);   float r = f[j] - bf2f(h0[j]);
        h1[j] = f2bf(r);      r -= bf2f(h1[j]);
        h2[j] = f2bf(r);
    }
    ((ushort4*)o0)[i] = make_ushort4(h0[0], h0[1], h0[2], h0[3]);
    ((ushort4*)o1)[i] = make_ushort4(h1[0], h1[1], h1[2], h1[3]);
    ((ushort4*)o2)[i] = make_ushort4(h2[0], h2[1], h2[2], h2[3]);
}

// W [512 k][512 n] f32 -> 3x bf16 transposed [512 n][512 k]
__global__ __launch_bounds__(256) void k_splitW(const float* __restrict__ W,
                                                unsigned short* __restrict__ w0,
                                                unsigned short* __restrict__ w1,
                                                unsigned short* __restrict__ w2) {
    __shared__ float tile[32][33];
    int bk = blockIdx.x * 32, bn = blockIdx.y * 32;
    int tx = threadIdx.x & 31, ty = threadIdx.x >> 5;  // ty 0..7
    #pragma unroll
    for (int r = 0; r < 4; ++r)
        tile[ty * 4 + r][tx] = W[(size_t)(bk + ty * 4 + r) * 512 + bn + tx];
    __syncthreads();
    #pragma unroll
    for (int r = 0; r < 4; ++r) {
        int n = bn + ty * 4 + r, k = bk + tx;
        float v = tile[tx][ty * 4 + r];
        unsigned short a0 = f2bf(v); float rr = v - bf2f(a0);
        unsigned short a1 = f2bf(rr); rr -= bf2f(a1);
        w0[(size_t)n * 512 + k] = a0;
        w1[(size_t)n * 512 + k] = a1;
        w2[(size_t)n * 512 + k] = f2bf(rr);
    }
}

// ---------------- MFMA GEMM: C(M x 512) = A(M x 512) @ B(512 x 512) ----------------
// A given as 3 bf16 components [c][M][512]; B as 3 bf16 components transposed [c][512 n][512 k].
// 6-product split => ~f32 accuracy. 128x128 tile, 4 waves (2x2), BK=32.
// Fragment-order LDS: slot (g*64+lane)*8 holds exactly lane's MFMA fragment -> all
// ds_read/ds_write linear, conflict-free. Reg-staged with next-K prefetch.

#define ASTR (NN * HDIM)     // elements per A component
#define BSTR (512 * 512)     // elements per B component

__global__ __launch_bounds__(256) void k_gemm_mfma(const unsigned short* __restrict__ S,
                                                   const unsigned short* __restrict__ Wt,
                                                   float* __restrict__ C, int M) {
    __shared__ short lds[6][4096];   // [0..2]=A comps, [3..5]=B comps; 48 KB
    const int t = threadIdx.x;
    const int lane = t & 63, wid = t >> 6;
    const int wr = wid >> 1, wc = wid & 1;
    const int bm = blockIdx.x * 128, bn = blockIdx.y * 128;
    const int arow = lane & 15, koff = (lane >> 4) * 8;

    // 48 staging units (16 rows x 32 k of one component), 12 per wave: 6 A + 6 B.
    int offA[6], offB[6], ldsA[6], ldsB[6];
    #pragma unroll
    for (int i = 0; i < 6; ++i) {
        int u = i * 4 + wid;           // 0..23
        int c = u >> 3, g = u & 7;
        int row = bm + g * 16 + arow; if (row >= M) row = M - 1;
        offA[i] = c * ASTR + row * HDIM + koff;
        ldsA[i] = c * 4096 + (g * 64 + lane) * 8;
    }
    #pragma unroll
    for (int i = 0; i < 6; ++i) {
        int u = i * 4 + wid;           // reuse 0..23 for B
        int c = u >> 3, g = u & 7;
        int row = bn + g * 16 + arow;
        offB[i] = c * BSTR + row * 512 + koff;
        ldsB[i] = (3 + c) * 4096 + (g * 64 + lane) * 8;
    }

    f32x4 acc[4][4];
    #pragma unroll
    for (int m = 0; m < 4; ++m)
        #pragma unroll
        for (int n = 0; n < 4; ++n) acc[m][n] = (f32x4){0.f, 0.f, 0.f, 0.f};

    s16x8 stA[6], stB[6];
    #pragma unroll
    for (int i = 0; i < 6; ++i) stA[i] = *(const s16x8*)(S + offA[i]);
    #pragma unroll
    for (int i = 0; i < 6; ++i) stB[i] = *(const s16x8*)(Wt + offB[i]);

    short* lp = &lds[0][0];
    #pragma unroll 1
    for (int s = 0; s < 16; ++s) {
        __syncthreads();
        #pragma unroll
        for (int i = 0; i < 6; ++i) *(s16x8*)(lp + ldsA[i]) = stA[i];
        #pragma unroll
        for (int i = 0; i < 6; ++i) *(s16x8*)(lp + ldsB[i]) = stB[i];
        if (s + 1 < 16) {
            int kadv = (s + 1) * 32;
            #pragma unroll
            for (int i = 0; i < 6; ++i) stA[i] = *(const s16x8*)(S + offA[i] + kadv);
            #pragma unroll
            for (int i = 0; i < 6; ++i) stB[i] = *(const s16x8*)(Wt + offB[i] + kadv);
        }
        __syncthreads();
        s16x8 af[3][4], bf[3][4];
        #pragma unroll
        for (int c = 0; c < 3; ++c)
            #pragma unroll
            for (int m = 0; m < 4; ++m)
                af[c][m] = *(const s16x8*)(lp + c * 4096 + ((wr * 4 + m) * 64 + lane) * 8);
        #pragma unroll
        for (int c = 0; c < 3; ++c)
            #pragma unroll
            for (int n = 0; n < 4; ++n)
                bf[c][n] = *(const s16x8*)(lp + (3 + c) * 4096 + ((wc * 4 + n) * 64 + lane) * 8);
        #pragma unroll
        for (int m = 0; m < 4; ++m)
            #pragma unroll
            for (int n = 0; n < 4; ++n) {
                acc[m][n] = __builtin_amdgcn_mfma_f32_16x16x32_bf16(af[0][m], bf[0][n], acc[m][n], 0, 0, 0);
                acc[m][n] = __builtin_amdgcn_mfma_f32_16x16x32_bf16(af[0][m], bf[1][n], acc[m][n], 0, 0, 0);
                acc[m][n] = __builtin_amdgcn_mfma_f32_16x16x32_bf16(af[1][m], bf[0][n], acc[m][n], 0, 0, 0);
                acc[m][n] = __builtin_amdgcn_mfma_f32_16x16x32_bf16(af[0][m], bf[2][n], acc[m][n], 0, 0, 0);
                acc[m][n] = __builtin_amdgcn_mfma_f32_16x16x32_bf16(af[1][m], bf[1][n], acc[m][n], 0, 0, 0);
                acc[m][n] = __builtin_amdgcn_mfma_f32_16x16x32_bf16(af[2][m], bf[0][n], acc[m][n], 0, 0, 0);
            }
    }

    // D mapping (m89-verified): col = lane&15, row = (lane>>4)*4 + reg
    int crow0 = bm + wr * 64 + (lane >> 4) * 4;
    int ccol0 = bn + wc * 64 + (lane & 15);
    #pragma unroll
    for (int m = 0; m < 4; ++m)
        #pragma unroll
        for (int n = 0; n < 4; ++n)
            #pragma unroll
            for (int r = 0; r < 4; ++r) {
                int row = crow0 + m * 16 + r;
                if (row < M) C[(size_t)row * 512 + ccol0 + n * 16] = acc[m][n][r];
            }
}

// ---------------- aggregation: one wave per node ----------------

__global__ __launch_bounds__(256) void k_agg(const float* __restrict__ h, const int* __restrict__ cstart,
                                             const int* __restrict__ csrc, const float* __restrict__ dinv,
                                             const float* __restrict__ bias, const float* __restrict__ res,
                                             float* __restrict__ out) {
    int w = blockIdx.x * 4 + (threadIdx.x >> 6);
    if (w >= NN) return;
    int lane = threadIdx.x & 63;
    float di = dinv[w];
    float acc[8] = {0, 0, 0, 0, 0, 0, 0, 0};
    int e0 = cstart[w], e1 = cstart[w + 1];
    for (int j = e0; j < e1; ++j) {
        int s = csrc[j];
        float wt = dinv[s] * di;
        const float* hr = h + (size_t)s * HDIM + lane * 8;
        float4 v0 = *(const float4*)hr;
        float4 v1 = *(const float4*)(hr + 4);
        acc[0] = fmaf(v0.x, wt, acc[0]); acc[1] = fmaf(v0.y, wt, acc[1]);
        acc[2] = fmaf(v0.z, wt, acc[2]); acc[3] = fmaf(v0.w, wt, acc[3]);
        acc[4] = fmaf(v1.x, wt, acc[4]); acc[5] = fmaf(v1.y, wt, acc[5]);
        acc[6] = fmaf(v1.z, wt, acc[6]); acc[7] = fmaf(v1.w, wt, acc[7]);
    }
    {
        float wt = di * di;
        const float* hr = h + (size_t)w * HDIM + lane * 8;
        float4 v0 = *(const float4*)hr;
        float4 v1 = *(const float4*)(hr + 4);
        acc[0] = fmaf(v0.x, wt, acc[0]); acc[1] = fmaf(v0.y, wt, acc[1]);
        acc[2] = fmaf(v0.z, wt, acc[2]); acc[3] = fmaf(v0.w, wt, acc[3]);
        acc[4] = fmaf(v1.x, wt, acc[4]); acc[5] = fmaf(v1.y, wt, acc[5]);
        acc[6] = fmaf(v1.z, wt, acc[6]); acc[7] = fmaf(v1.w, wt, acc[7]);
    }
    const float* bptr = bias + lane * 8;
    const float* rptr = res ? res + (size_t)w * HDIM + lane * 8 : nullptr;
    float v[8];
    #pragma unroll
    for (int q = 0; q < 8; ++q) {
        float t = acc[q] + bptr[q];
        if (rptr) t += rptr[q];
        v[q] = t > 0.f ? t : (expf(t) - 1.f);
    }
    float* orow = out + (size_t)w * HDIM + lane * 8;
    *(float4*)orow       = make_float4(v[0], v[1], v[2], v[3]);
    *(float4*)(orow + 4) = make_float4(v[4], v[5], v[6], v[7]);
}

// ---------------- layer 3: h3 = x2 @ W3 (512 -> 1), wave per node ----------------

__global__ __launch_bounds__(256) void k_gemv3(const float* __restrict__ x2, const float* __restrict__ W3,
                                               float* __restrict__ h3) {
    int w = blockIdx.x * 4 + (threadIdx.x >> 6);
    if (w >= NN) return;
    int lane = threadIdx.x & 63;
    const float* r = x2 + (size_t)w * HDIM + lane * 8;
    const float* wp = W3 + lane * 8;
    float4 a0 = *(const float4*)r, a1 = *(const float4*)(r + 4);
    float4 w0 = *(const float4*)wp, w1 = *(const float4*)(wp + 4);
    float acc = a0.x * w0.x + a0.y * w0.y + a0.z * w0.z + a0.w * w0.w
              + a1.x * w1.x + a1.y * w1.y + a1.z * w1.z + a1.w * w1.w;
    #pragma unroll
    for (int off = 32; off; off >>= 1) acc += __shfl_down(acc, off);
    if (lane == 0) h3[w] = acc;
}

__global__ void k_agg3(const float* __restrict__ h3, const int* __restrict__ cstart,
                       const int* __restrict__ csrc, const float* __restrict__ dinv,
                       const float* __restrict__ b3, float* __restrict__ key) {
    int i = blockIdx.x * 256 + threadIdx.x;
    if (i >= NN) return;
    float di = dinv[i];
    float acc = h3[i] * di * di;
    int e0 = cstart[i], e1 = cstart[i + 1];
    for (int j = e0; j < e1; ++j) {
        int s = csrc[j];
        acc = fmaf(h3[s], dinv[s] * di, acc);
    }
    key[i] = acc + b3[0];
}

// ---------------- sort-pool ----------------

#define MAXN 2048
__global__ __launch_bounds__(256) void k_select(const float* __restrict__ key, const int* __restrict__ gstart,
                                                int* __restrict__ sel) {
    int g = blockIdx.x;
    int s = gstart[g], e = gstart[g + 1];
    int cnt = e - s;
    if (cnt > MAXN) cnt = MAXN;
    __shared__ float ks[MAXN];
    __shared__ int sels[KTOP];
    for (int i = threadIdx.x; i < cnt; i += 256) ks[i] = key[s + i];
    if (threadIdx.x < KTOP) sels[threadIdx.x] = -1;
    __syncthreads();
    for (int i = threadIdx.x; i < cnt; i += 256) {
        float ki = ks[i];
        int r = 0;
        for (int j = 0; j < cnt; ++j) {
            float kj = ks[j];
            r += (kj > ki) || (kj == ki && j < i);
        }
        if (r < KTOP) sels[r] = s + i;
    }
    __syncthreads();
    if (threadIdx.x < KTOP) sel[g * KTOP + threadIdx.x] = sels[threadIdx.x];
}

// ---------------- conv1: one block per (graph, position) ----------------

__global__ __launch_bounds__(256) void k_conv1(const float* __restrict__ x1, const float* __restrict__ x2,
                                               const float* __restrict__ key, const int* __restrict__ sel,
                                               const float* __restrict__ cw1, const float* __restrict__ cb1,
                                               float* __restrict__ c1) {
    int gp = blockIdx.x;
    int g = gp / KTOP, p = gp - g * KTOP;
    int t = threadIdx.x;
    int node = sel[gp];
    if (node < 0) {
        if (t < 16) c1[((size_t)g * 16 + t) * KTOP + p] = fmaxf(cb1[t], 0.f);
        return;
    }
    __shared__ float f[1025];
    __shared__ float red[16][17];
    if (t < 128) {
        ((float4*)f)[t] = ((const float4*)(x1 + (size_t)node * HDIM))[t];
    } else {
        ((float4*)(f + 512))[t - 128] = ((const float4*)(x2 + (size_t)node * HDIM))[t - 128];
    }
    if (t == 0) f[1024] = key[node];
    __syncthreads();
    int oc = t >> 4, ch = t & 15;
    const float* wrow = cw1 + (size_t)oc * 1025;
    float pd = 0.f;
    for (int k = ch; k < 1025; k += 16) pd = fmaf(f[k], wrow[k], pd);
    red[oc][ch] = pd;
    __syncthreads();
    if (t < 16) {
        float ssum = cb1[t];
        #pragma unroll
        for (int c = 0; c < 16; ++c) ssum += red[t][c];
        c1[((size_t)g * 16 + t) * KTOP + p] = fmaxf(ssum, 0.f);
    }
}

// ---------------- fused head ----------------

__global__ __launch_bounds__(512) void k_head(const float* __restrict__ c1, const float* __restrict__ cw2,
                                              const float* __restrict__ cb2, const float* __restrict__ lw1,
                                              const float* __restrict__ lb1, const float* __restrict__ lw2,
                                              const float* __restrict__ lb2, float* __restrict__ outp) {
    int g = blockIdx.x, t = threadIdx.x;
    __shared__ float m[16][15];
    __shared__ float z2s[352];
    __shared__ float z3[512];
    if (t < 240) {
        int ic = t / 15, q = t % 15;
        const float* row = c1 + ((size_t)g * 16 + ic) * KTOP;
        m[ic][q] = fmaxf(row[2 * q], row[2 * q + 1]);
    }
    __syncthreads();
    if (t < 352) {
        int oc = t / 11, tt = t % 11;
        float acc = cb2[oc];
        #pragma unroll
        for (int ic = 0; ic < 16; ++ic)
            #pragma unroll
            for (int j = 0; j < 5; ++j)
                acc = fmaf(m[ic][tt + j], cw2[((size_t)oc * 16 + ic) * 5 + j], acc);
        z2s[t] = fmaxf(acc, 0.f);
    }
    __syncthreads();
    {
        float acc = lb1[t];
        for (int k = 0; k < 352; ++k) acc = fmaf(z2s[k], lw1[(size_t)k * 512 + t], acc);
        z3[t] = fmaxf(acc, 0.f);
    }
    __syncthreads();
    if (t < 160) {
        int oc = t >> 4, l = t & 15;
        float acc = 0.f;
        for (int k = l; k < 512; k += 16) acc = fmaf(z3[k], lw2[(size_t)k * 10 + oc], acc);
        #pragma unroll
        for (int off = 1; off < 16; off <<= 1) acc += __shfl_xor(acc, off);
        if (l == 0) outp[g * 10 + oc] = acc + lb2[oc];
    }
}

// ---------------- launch ----------------

extern "C" void kernel_launch(void* const* d_in, const int* in_sizes, int n_in,
                              void* d_out, int out_size, void* d_ws, size_t ws_size,
                              hipStream_t stream) {
    const float* x    = (const float*)d_in[0];
    const int*   ei   = (const int*)d_in[1];
    const int*   batch= (const int*)d_in[2];
    const float* W1   = (const float*)d_in[3];
    const float* b1   = (const float*)d_in[4];
    const float* W2   = (const float*)d_in[5];
    const float* b2   = (const float*)d_in[6];
    const float* W3   = (const float*)d_in[7];
    const float* b3   = (const float*)d_in[8];
    const float* cw1  = (const float*)d_in[9];
    const float* cb1  = (const float*)d_in[10];
    const float* cw2  = (const float*)d_in[11];
    const float* cb2  = (const float*)d_in[12];
    const float* lw1  = (const float*)d_in[13];
    const float* lb1  = (const float*)d_in[14];
    const float* lw2  = (const float*)d_in[15];
    const float* lb2  = (const float*)d_in[16];

    const int NE = in_sizes[1] / 2;
    const int* srcp = ei;
    const int* dstp = ei + NE;

    char* ws = (char*)d_ws;
    size_t o = 0;
    auto al = [&](size_t b) { size_t r = o; o += (b + 255) & ~(size_t)255; return r; };
    int*   indeg  = (int*)(ws + al((size_t)NN * 4));
    int*   ccur   = (int*)(ws + al((size_t)NN * 4));
    int*   cstart = (int*)(ws + al((size_t)(NN + 1) * 4));
    int*   csrc   = (int*)(ws + al((size_t)NE * 4));
    float* dinv   = (float*)(ws + al((size_t)NN * 4));
    float* h      = (float*)(ws + al((size_t)NN * HDIM * 4));
    float* x1     = (float*)(ws + al((size_t)NN * HDIM * 4));
    float* h3     = (float*)(ws + al((size_t)NN * 4));
    float* key    = (float*)(ws + al((size_t)NN * 4));
    int*   gcnt   = (int*)(ws + al((size_t)NG * 4));
    int*   gstart = (int*)(ws + al((size_t)(NG + 1) * 4));
    int*   sel    = (int*)(ws + al((size_t)NG * KTOP * 4));
    float* c1     = (float*)(ws + al((size_t)NG * 16 * KTOP * 4));
    unsigned short* S  = (unsigned short*)(ws + al((size_t)3 * NN * HDIM * 2));   // 61.4 MB split buf
    unsigned short* Wt = (unsigned short*)(ws + al((size_t)3 * 512 * 512 * 2));   // 1.6 MB
    // x2 aliases S: S is dead after gemm2 reads it; agg2 then writes x2 here.
    float* x2 = (float*)S;
    (void)ws_size; (void)n_in; (void)out_size;

    int nb_n = (NN + 255) / 256;
    int nb_e = (NE + 255) / 256;

    k_init<<<nb_n, 256, 0, stream>>>(indeg, ccur, gcnt);
    k_count<<<nb_e, 256, 0, stream>>>(dstp, indeg, NE);
    k_gcount<<<nb_n, 256, 0, stream>>>(batch, gcnt);
    k_dinv<<<nb_n, 256, 0, stream>>>(indeg, dinv);
    k_scan<<<1, 256, 0, stream>>>(indeg, cstart, NN);
    k_scan<<<1, 256, 0, stream>>>(gcnt, gstart, NG);
    k_fill<<<nb_e, 256, 0, stream>>>(srcp, dstp, cstart, ccur, csrc, NE);

    const int n4 = NN * HDIM / 4;
    const int nsp = (n4 + 255) / 256;
    dim3 gw(16, 16);
    dim3 gg((NN + 127) / 128, 4);

    // layer 1
    k_split<<<nsp, 256, 0, stream>>>(x, S, S + (size_t)NN * HDIM, S + (size_t)2 * NN * HDIM, n4);
    k_splitW<<<gw, 256, 0, stream>>>(W1, Wt, Wt + 512 * 512, Wt + 2 * 512 * 512);
    k_gemm_mfma<<<gg, 256, 0, stream>>>(S, Wt, h, NN);
    k_agg<<<NN / 4, 256, 0, stream>>>(h, cstart, csrc, dinv, b1, nullptr, x1);
    // layer 2
    k_split<<<nsp, 256, 0, stream>>>(x1, S, S + (size_t)NN * HDIM, S + (size_t)2 * NN * HDIM, n4);
    k_splitW<<<gw, 256, 0, stream>>>(W2, Wt, Wt + 512 * 512, Wt + 2 * 512 * 512);
    k_gemm_mfma<<<gg, 256, 0, stream>>>(S, Wt, h, NN);
    k_agg<<<NN / 4, 256, 0, stream>>>(h, cstart, csrc, dinv, b2, x1, x2);  // overwrites S (dead)
    // layer 3 + pool + head
    k_gemv3<<<NN / 4, 256, 0, stream>>>(x2, W3, h3);
    k_agg3<<<nb_n, 256, 0, stream>>>(h3, cstart, csrc, dinv, b3, key);
    k_select<<<NG, 256, 0, stream>>>(key, gstart, sel);
    k_conv1<<<NG * KTOP, 256, 0, stream>>>(x1, x2, key, sel, cw1, cb1, c1);
    k_head<<<NG, 512, 0, stream>>>(c1, cw2, cb2, lw1, lb1, lw2, lb2, (float*)d_out);
}

// Round 12
// 672.166 us; speedup vs baseline: 1.5048x; 1.0176x over previous
//
#include <hip/hip_runtime.h>
#include <hip/hip_bf16.h>

#define NN 20000
#define NEDGE 200000
#define NG 500
#define KTOP 30
#define HDIM 512

typedef __attribute__((ext_vector_type(8))) short s16x8;
typedef __attribute__((ext_vector_type(4))) float f32x4;

__device__ __forceinline__ unsigned short f2bf(float f) {
    unsigned int u = __float_as_uint(f);
    return (unsigned short)((u + 0x7FFFu + ((u >> 16) & 1u)) >> 16);
}
__device__ __forceinline__ float bf2f(unsigned short s) {
    return __uint_as_float(((unsigned int)s) << 16);
}

// ---------------- setup kernels ----------------

__global__ void k_init(int* indeg, int* ccur, int* gcnt) {
    int i = blockIdx.x * 256 + threadIdx.x;
    if (i < NN) { indeg[i] = 0; ccur[i] = 0; }
    if (i < NG) gcnt[i] = 0;
}

__global__ void k_count(const int* __restrict__ dst, int* indeg, int ne) {
    int e = blockIdx.x * 256 + threadIdx.x;
    if (e < ne) atomicAdd(&indeg[dst[e]], 1);
}

__global__ void k_gcount(const int* __restrict__ batch, int* gcnt) {
    int i = blockIdx.x * 256 + threadIdx.x;
    if (i < NN) atomicAdd(&gcnt[batch[i]], 1);
}

__global__ void k_dinv(const int* __restrict__ indeg, float* dinv) {
    int i = blockIdx.x * 256 + threadIdx.x;
    if (i < NN) dinv[i] = rsqrtf((float)(indeg[i] + 1));
}

__global__ void k_scan(const int* __restrict__ in, int* __restrict__ out, int n) {
    const int NT = 256;
    __shared__ int sums[NT];
    int t = threadIdx.x;
    int per = (n + NT - 1) / NT;
    int s0 = t * per;
    int local = 0;
    for (int k = 0; k < per; ++k) { int idx = s0 + k; if (idx < n) local += in[idx]; }
    sums[t] = local;
    __syncthreads();
    for (int off = 1; off < NT; off <<= 1) {
        int v = (t >= off) ? sums[t - off] : 0;
        __syncthreads();
        sums[t] += v;
        __syncthreads();
    }
    int run = sums[t] - local;
    for (int k = 0; k < per; ++k) { int idx = s0 + k; if (idx < n) { out[idx] = run; run += in[idx]; } }
    if (t == NT - 1) out[n] = run;
}

__global__ void k_fill(const int* __restrict__ src, const int* __restrict__ dst,
                       const int* __restrict__ cstart, int* ccur, int* csrc, int ne) {
    int e = blockIdx.x * 256 + threadIdx.x;
    if (e < ne) {
        int d = dst[e];
        int pos = cstart[d] + atomicAdd(&ccur[d], 1);
        csrc[pos] = src[e];
    }
}

// ---------------- split passes: f32 -> 3x bf16 (hi/mid/lo) ----------------

__global__ __launch_bounds__(256) void k_split(const float* __restrict__ A,
                                               unsigned short* __restrict__ o0,
                                               unsigned short* __restrict__ o1,
                                               unsigned short* __restrict__ o2, int n4) {
    int i = blockIdx.x * 256 + threadIdx.x;
    if (i >= n4) return;
    float4 v = ((const float4*)A)[i];
    float f[4] = {v.x, v.y, v.z, v.w};
    unsigned short h0[4], h1[4], h2[4];
    #pragma unroll
    for (int j = 0; j < 4; ++j) {
        h0[j] = f2bf(f[j]);   float r = f[j] - bf2f(h0[j]);
        h1[j] = f2bf(r);      r -= bf2f(h1[j]);
        h2[j] = f2bf(r);
    }
    ((ushort4*)o0)[i] = make_ushort4(h0[0], h0[1], h0[2], h0[3]);
    ((ushort4*)o1)[i] = make_ushort4(h1[0], h1[1], h1[2], h1[3]);
    ((ushort4*)o2)[i] = make_ushort4(h2[0], h2[1], h2[2], h2[3]);
}

// W [512 k][512 n] f32 -> 3x bf16 transposed [512 n][512 k]
__global__ __launch_bounds__(256) void k_splitW(const float* __restrict__ W,
                                                unsigned short* __restrict__ w0,
                                                unsigned short* __restrict__ w1,
                                                unsigned short* __restrict__ w2) {
    __shared__ float tile[32][33];
    int bk = blockIdx.x * 32, bn = blockIdx.y * 32;
    int tx = threadIdx.x & 31, ty = threadIdx.x >> 5;
    #pragma unroll
    for (int r = 0; r < 4; ++r)
        tile[ty * 4 + r][tx] = W[(size_t)(bk + ty * 4 + r) * 512 + bn + tx];
    __syncthreads();
    #pragma unroll
    for (int r = 0; r < 4; ++r) {
        int n = bn + ty * 4 + r, k = bk + tx;
        float v = tile[tx][ty * 4 + r];
        unsigned short a0 = f2bf(v); float rr = v - bf2f(a0);
        unsigned short a1 = f2bf(rr); rr -= bf2f(a1);
        w0[(size_t)n * 512 + k] = a0;
        w1[(size_t)n * 512 + k] = a1;
        w2[(size_t)n * 512 + k] = f2bf(rr);
    }
}

// ---------------- MFMA GEMM: C(M x 512) = A(M x 512) @ B(512 x 512) ----------------
// 64x128 tile (more blocks -> higher CU occupancy than 128x128), 4 waves (2x2),
// BK=32, 6-product bf16 split = ~f32 accuracy. Fragment-order LDS: slot
// (g*64+lane)*8 is exactly lane's MFMA fragment -> linear, conflict-free
// (verified: SQ_LDS_BANK_CONFLICT=0). Reg-staged next-K prefetch.

#define ASTR (NN * HDIM)
#define BSTR (512 * 512)

__global__ __launch_bounds__(256) void k_gemm_mfma(const unsigned short* __restrict__ S,
                                                   const unsigned short* __restrict__ Wt,
                                                   float* __restrict__ C, int M) {
    __shared__ short lds[18432];   // A: 3*64*32 = 6144, B: 3*128*32 = 12288; 36 KB
    const int t = threadIdx.x;
    const int lane = t & 63, wid = t >> 6;
    const int wr = wid >> 1, wc = wid & 1;
    const int bm = blockIdx.x * 64, bn = blockIdx.y * 128;
    const int arow = lane & 15, koff = (lane >> 4) * 8;

    // staging: A 12 units (c 0..2, g 0..3), B 24 units (c 0..2, g 0..7); per wave 3 A + 6 B
    int offA[3], offB[6], ldsA[3], ldsB[6];
    #pragma unroll
    for (int i = 0; i < 3; ++i) {
        int u = i * 4 + wid;             // 0..11
        int c = u >> 2, g = u & 3;
        int row = bm + g * 16 + arow; if (row >= M) row = M - 1;
        offA[i] = c * ASTR + row * HDIM + koff;
        ldsA[i] = c * 2048 + (g * 64 + lane) * 8;
    }
    #pragma unroll
    for (int i = 0; i < 6; ++i) {
        int u = i * 4 + wid;             // 0..23
        int c = u >> 3, g = u & 7;
        int row = bn + g * 16 + arow;
        offB[i] = c * BSTR + row * 512 + koff;
        ldsB[i] = 6144 + c * 4096 + (g * 64 + lane) * 8;
    }

    f32x4 acc[2][4];
    #pragma unroll
    for (int m = 0; m < 2; ++m)
        #pragma unroll
        for (int n = 0; n < 4; ++n) acc[m][n] = (f32x4){0.f, 0.f, 0.f, 0.f};

    s16x8 stA[3], stB[6];
    #pragma unroll
    for (int i = 0; i < 3; ++i) stA[i] = *(const s16x8*)(S + offA[i]);
    #pragma unroll
    for (int i = 0; i < 6; ++i) stB[i] = *(const s16x8*)(Wt + offB[i]);

    short* lp = lds;
    #pragma unroll 1
    for (int s = 0; s < 16; ++s) {
        __syncthreads();
        #pragma unroll
        for (int i = 0; i < 3; ++i) *(s16x8*)(lp + ldsA[i]) = stA[i];
        #pragma unroll
        for (int i = 0; i < 6; ++i) *(s16x8*)(lp + ldsB[i]) = stB[i];
        if (s + 1 < 16) {
            int kadv = (s + 1) * 32;
            #pragma unroll
            for (int i = 0; i < 3; ++i) stA[i] = *(const s16x8*)(S + offA[i] + kadv);
            #pragma unroll
            for (int i = 0; i < 6; ++i) stB[i] = *(const s16x8*)(Wt + offB[i] + kadv);
        }
        __syncthreads();
        s16x8 af[3][2], bf[3][4];
        #pragma unroll
        for (int c = 0; c < 3; ++c)
            #pragma unroll
            for (int m = 0; m < 2; ++m)
                af[c][m] = *(const s16x8*)(lp + c * 2048 + ((wr * 2 + m) * 64 + lane) * 8);
        #pragma unroll
        for (int c = 0; c < 3; ++c)
            #pragma unroll
            for (int n = 0; n < 4; ++n)
                bf[c][n] = *(const s16x8*)(lp + 6144 + c * 4096 + ((wc * 4 + n) * 64 + lane) * 8);
        #pragma unroll
        for (int m = 0; m < 2; ++m)
            #pragma unroll
            for (int n = 0; n < 4; ++n) {
                acc[m][n] = __builtin_amdgcn_mfma_f32_16x16x32_bf16(af[0][m], bf[0][n], acc[m][n], 0, 0, 0);
                acc[m][n] = __builtin_amdgcn_mfma_f32_16x16x32_bf16(af[0][m], bf[1][n], acc[m][n], 0, 0, 0);
                acc[m][n] = __builtin_amdgcn_mfma_f32_16x16x32_bf16(af[1][m], bf[0][n], acc[m][n], 0, 0, 0);
                acc[m][n] = __builtin_amdgcn_mfma_f32_16x16x32_bf16(af[0][m], bf[2][n], acc[m][n], 0, 0, 0);
                acc[m][n] = __builtin_amdgcn_mfma_f32_16x16x32_bf16(af[1][m], bf[1][n], acc[m][n], 0, 0, 0);
                acc[m][n] = __builtin_amdgcn_mfma_f32_16x16x32_bf16(af[2][m], bf[0][n], acc[m][n], 0, 0, 0);
            }
    }

    int crow0 = bm + wr * 32 + (lane >> 4) * 4;
    int ccol0 = bn + wc * 64 + (lane & 15);
    #pragma unroll
    for (int m = 0; m < 2; ++m)
        #pragma unroll
        for (int n = 0; n < 4; ++n)
            #pragma unroll
            for (int r = 0; r < 4; ++r) {
                int row = crow0 + m * 16 + r;
                if (row < M) C[(size_t)row * 512 + ccol0 + n * 16] = acc[m][n][r];
            }
}

// ---------------- aggregation: one wave per node, 2-edge unroll ----------------
// optional fused bf16 3-split of the output (replaces a separate k_split pass)

__global__ __launch_bounds__(256) void k_agg(const float* __restrict__ h, const int* __restrict__ cstart,
                                             const int* __restrict__ csrc, const float* __restrict__ dinv,
                                             const float* __restrict__ bias, const float* __restrict__ res,
                                             float* __restrict__ out,
                                             unsigned short* __restrict__ o0,
                                             unsigned short* __restrict__ o1,
                                             unsigned short* __restrict__ o2) {
    int w = blockIdx.x * 4 + (threadIdx.x >> 6);
    if (w >= NN) return;
    int lane = threadIdx.x & 63;
    float di = dinv[w];
    float acc[8] = {0, 0, 0, 0, 0, 0, 0, 0};
    float acc2[8] = {0, 0, 0, 0, 0, 0, 0, 0};
    int e0 = cstart[w], e1 = cstart[w + 1];
    int j = e0;
    for (; j + 1 < e1; j += 2) {
        int s0 = csrc[j], s1 = csrc[j + 1];
        float wt0 = dinv[s0] * di, wt1 = dinv[s1] * di;
        const float* hr0 = h + (size_t)s0 * HDIM + lane * 8;
        const float* hr1 = h + (size_t)s1 * HDIM + lane * 8;
        float4 a0 = *(const float4*)hr0, a1 = *(const float4*)(hr0 + 4);
        float4 b0 = *(const float4*)hr1, b1 = *(const float4*)(hr1 + 4);
        acc[0] = fmaf(a0.x, wt0, acc[0]); acc[1] = fmaf(a0.y, wt0, acc[1]);
        acc[2] = fmaf(a0.z, wt0, acc[2]); acc[3] = fmaf(a0.w, wt0, acc[3]);
        acc[4] = fmaf(a1.x, wt0, acc[4]); acc[5] = fmaf(a1.y, wt0, acc[5]);
        acc[6] = fmaf(a1.z, wt0, acc[6]); acc[7] = fmaf(a1.w, wt0, acc[7]);
        acc2[0] = fmaf(b0.x, wt1, acc2[0]); acc2[1] = fmaf(b0.y, wt1, acc2[1]);
        acc2[2] = fmaf(b0.z, wt1, acc2[2]); acc2[3] = fmaf(b0.w, wt1, acc2[3]);
        acc2[4] = fmaf(b1.x, wt1, acc2[4]); acc2[5] = fmaf(b1.y, wt1, acc2[5]);
        acc2[6] = fmaf(b1.z, wt1, acc2[6]); acc2[7] = fmaf(b1.w, wt1, acc2[7]);
    }
    if (j < e1) {
        int s = csrc[j];
        float wt = dinv[s] * di;
        const float* hr = h + (size_t)s * HDIM + lane * 8;
        float4 v0 = *(const float4*)hr;
        float4 v1 = *(const float4*)(hr + 4);
        acc[0] = fmaf(v0.x, wt, acc[0]); acc[1] = fmaf(v0.y, wt, acc[1]);
        acc[2] = fmaf(v0.z, wt, acc[2]); acc[3] = fmaf(v0.w, wt, acc[3]);
        acc[4] = fmaf(v1.x, wt, acc[4]); acc[5] = fmaf(v1.y, wt, acc[5]);
        acc[6] = fmaf(v1.z, wt, acc[6]); acc[7] = fmaf(v1.w, wt, acc[7]);
    }
    {
        float wt = di * di;
        const float* hr = h + (size_t)w * HDIM + lane * 8;
        float4 v0 = *(const float4*)hr;
        float4 v1 = *(const float4*)(hr + 4);
        acc[0] = fmaf(v0.x, wt, acc[0]); acc[1] = fmaf(v0.y, wt, acc[1]);
        acc[2] = fmaf(v0.z, wt, acc[2]); acc[3] = fmaf(v0.w, wt, acc[3]);
        acc[4] = fmaf(v1.x, wt, acc[4]); acc[5] = fmaf(v1.y, wt, acc[5]);
        acc[6] = fmaf(v1.z, wt, acc[6]); acc[7] = fmaf(v1.w, wt, acc[7]);
    }
    const float* bptr = bias + lane * 8;
    const float* rptr = res ? res + (size_t)w * HDIM + lane * 8 : nullptr;
    float v[8];
    #pragma unroll
    for (int q = 0; q < 8; ++q) {
        float tt = acc[q] + acc2[q] + bptr[q];
        if (rptr) tt += rptr[q];
        v[q] = tt > 0.f ? tt : (expf(tt) - 1.f);
    }
    float* orow = out + (size_t)w * HDIM + lane * 8;
    *(float4*)orow       = make_float4(v[0], v[1], v[2], v[3]);
    *(float4*)(orow + 4) = make_float4(v[4], v[5], v[6], v[7]);
    if (o0) {
        unsigned short h0[8], h1[8], h2[8];
        #pragma unroll
        for (int q = 0; q < 8; ++q) {
            h0[q] = f2bf(v[q]);  float r = v[q] - bf2f(h0[q]);
            h1[q] = f2bf(r);     r -= bf2f(h1[q]);
            h2[q] = f2bf(r);
        }
        size_t base = (size_t)w * HDIM + lane * 8;
        *(ushort4*)(o0 + base)     = make_ushort4(h0[0], h0[1], h0[2], h0[3]);
        *(ushort4*)(o0 + base + 4) = make_ushort4(h0[4], h0[5], h0[6], h0[7]);
        *(ushort4*)(o1 + base)     = make_ushort4(h1[0], h1[1], h1[2], h1[3]);
        *(ushort4*)(o1 + base + 4) = make_ushort4(h1[4], h1[5], h1[6], h1[7]);
        *(ushort4*)(o2 + base)     = make_ushort4(h2[0], h2[1], h2[2], h2[3]);
        *(ushort4*)(o2 + base + 4) = make_ushort4(h2[4], h2[5], h2[6], h2[7]);
    }
}

// ---------------- layer 3: h3 = x2 @ W3 (512 -> 1), wave per node ----------------

__global__ __launch_bounds__(256) void k_gemv3(const float* __restrict__ x2, const float* __restrict__ W3,
                                               float* __restrict__ h3) {
    int w = blockIdx.x * 4 + (threadIdx.x >> 6);
    if (w >= NN) return;
    int lane = threadIdx.x & 63;
    const float* r = x2 + (size_t)w * HDIM + lane * 8;
    const float* wp = W3 + lane * 8;
    float4 a0 = *(const float4*)r, a1 = *(const float4*)(r + 4);
    float4 w0 = *(const float4*)wp, w1 = *(const float4*)(wp + 4);
    float acc = a0.x * w0.x + a0.y * w0.y + a0.z * w0.z + a0.w * w0.w
              + a1.x * w1.x + a1.y * w1.y + a1.z * w1.z + a1.w * w1.w;
    #pragma unroll
    for (int off = 32; off; off >>= 1) acc += __shfl_down(acc, off);
    if (lane == 0) h3[w] = acc;
}

__global__ void k_agg3(const float* __restrict__ h3, const int* __restrict__ cstart,
                       const int* __restrict__ csrc, const float* __restrict__ dinv,
                       const float* __restrict__ b3, float* __restrict__ key) {
    int i = blockIdx.x * 256 + threadIdx.x;
    if (i >= NN) return;
    float di = dinv[i];
    float acc = h3[i] * di * di;
    int e0 = cstart[i], e1 = cstart[i + 1];
    for (int j = e0; j < e1; ++j) {
        int s = csrc[j];
        acc = fmaf(h3[s], dinv[s] * di, acc);
    }
    key[i] = acc + b3[0];
}

// ---------------- sort-pool ----------------

#define MAXN 2048
__global__ __launch_bounds__(256) void k_select(const float* __restrict__ key, const int* __restrict__ gstart,
                                                int* __restrict__ sel) {
    int g = blockIdx.x;
    int s = gstart[g], e = gstart[g + 1];
    int cnt = e - s;
    if (cnt > MAXN) cnt = MAXN;
    __shared__ float ks[MAXN];
    __shared__ int sels[KTOP];
    for (int i = threadIdx.x; i < cnt; i += 256) ks[i] = key[s + i];
    if (threadIdx.x < KTOP) sels[threadIdx.x] = -1;
    __syncthreads();
    for (int i = threadIdx.x; i < cnt; i += 256) {
        float ki = ks[i];
        int r = 0;
        for (int j = 0; j < cnt; ++j) {
            float kj = ks[j];
            r += (kj > ki) || (kj == ki && j < i);
        }
        if (r < KTOP) sels[r] = s + i;
    }
    __syncthreads();
    if (threadIdx.x < KTOP) sel[g * KTOP + threadIdx.x] = sels[threadIdx.x];
}

// ---------------- conv1: one block per (graph, position) ----------------

__global__ __launch_bounds__(256) void k_conv1(const float* __restrict__ x1, const float* __restrict__ x2,
                                               const float* __restrict__ key, const int* __restrict__ sel,
                                               const float* __restrict__ cw1, const float* __restrict__ cb1,
                                               float* __restrict__ c1) {
    int gp = blockIdx.x;
    int g = gp / KTOP, p = gp - g * KTOP;
    int t = threadIdx.x;
    int node = sel[gp];
    if (node < 0) {
        if (t < 16) c1[((size_t)g * 16 + t) * KTOP + p] = fmaxf(cb1[t], 0.f);
        return;
    }
    __shared__ float f[1025];
    __shared__ float red[16][17];
    if (t < 128) {
        ((float4*)f)[t] = ((const float4*)(x1 + (size_t)node * HDIM))[t];
    } else {
        ((float4*)(f + 512))[t - 128] = ((const float4*)(x2 + (size_t)node * HDIM))[t - 128];
    }
    if (t == 0) f[1024] = key[node];
    __syncthreads();
    int oc = t >> 4, ch = t & 15;
    const float* wrow = cw1 + (size_t)oc * 1025;
    float pd = 0.f;
    for (int k = ch; k < 1025; k += 16) pd = fmaf(f[k], wrow[k], pd);
    red[oc][ch] = pd;
    __syncthreads();
    if (t < 16) {
        float ssum = cb1[t];
        #pragma unroll
        for (int c = 0; c < 16; ++c) ssum += red[t][c];
        c1[((size_t)g * 16 + t) * KTOP + p] = fmaxf(ssum, 0.f);
    }
}

// ---------------- fused head ----------------

__global__ __launch_bounds__(512) void k_head(const float* __restrict__ c1, const float* __restrict__ cw2,
                                              const float* __restrict__ cb2, const float* __restrict__ lw1,
                                              const float* __restrict__ lb1, const float* __restrict__ lw2,
                                              const float* __restrict__ lb2, float* __restrict__ outp) {
    int g = blockIdx.x, t = threadIdx.x;
    __shared__ float m[16][15];
    __shared__ float z2s[352];
    __shared__ float z3[512];
    if (t < 240) {
        int ic = t / 15, q = t % 15;
        const float* row = c1 + ((size_t)g * 16 + ic) * KTOP;
        m[ic][q] = fmaxf(row[2 * q], row[2 * q + 1]);
    }
    __syncthreads();
    if (t < 352) {
        int oc = t / 11, tt = t % 11;
        float acc = cb2[oc];
        #pragma unroll
        for (int ic = 0; ic < 16; ++ic)
            #pragma unroll
            for (int j = 0; j < 5; ++j)
                acc = fmaf(m[ic][tt + j], cw2[((size_t)oc * 16 + ic) * 5 + j], acc);
        z2s[t] = fmaxf(acc, 0.f);
    }
    __syncthreads();
    {
        float acc = lb1[t];
        for (int k = 0; k < 352; ++k) acc = fmaf(z2s[k], lw1[(size_t)k * 512 + t], acc);
        z3[t] = fmaxf(acc, 0.f);
    }
    __syncthreads();
    if (t < 160) {
        int oc = t >> 4, l = t & 15;
        float acc = 0.f;
        for (int k = l; k < 512; k += 16) acc = fmaf(z3[k], lw2[(size_t)k * 10 + oc], acc);
        #pragma unroll
        for (int off = 1; off < 16; off <<= 1) acc += __shfl_xor(acc, off);
        if (l == 0) outp[g * 10 + oc] = acc + lb2[oc];
    }
}

// ---------------- launch ----------------

extern "C" void kernel_launch(void* const* d_in, const int* in_sizes, int n_in,
                              void* d_out, int out_size, void* d_ws, size_t ws_size,
                              hipStream_t stream) {
    const float* x    = (const float*)d_in[0];
    const int*   ei   = (const int*)d_in[1];
    const int*   batch= (const int*)d_in[2];
    const float* W1   = (const float*)d_in[3];
    const float* b1   = (const float*)d_in[4];
    const float* W2   = (const float*)d_in[5];
    const float* b2   = (const float*)d_in[6];
    const float* W3   = (const float*)d_in[7];
    const float* b3   = (const float*)d_in[8];
    const float* cw1  = (const float*)d_in[9];
    const float* cb1  = (const float*)d_in[10];
    const float* cw2  = (const float*)d_in[11];
    const float* cb2  = (const float*)d_in[12];
    const float* lw1  = (const float*)d_in[13];
    const float* lb1  = (const float*)d_in[14];
    const float* lw2  = (const float*)d_in[15];
    const float* lb2  = (const float*)d_in[16];

    const int NE = in_sizes[1] / 2;
    const int* srcp = ei;
    const int* dstp = ei + NE;

    char* ws = (char*)d_ws;
    size_t o = 0;
    auto al = [&](size_t b) { size_t r = o; o += (b + 255) & ~(size_t)255; return r; };
    int*   indeg  = (int*)(ws + al((size_t)NN * 4));
    int*   ccur   = (int*)(ws + al((size_t)NN * 4));
    int*   cstart = (int*)(ws + al((size_t)(NN + 1) * 4));
    int*   csrc   = (int*)(ws + al((size_t)NE * 4));
    float* dinv   = (float*)(ws + al((size_t)NN * 4));
    float* h      = (float*)(ws + al((size_t)NN * HDIM * 4));
    float* x1     = (float*)(ws + al((size_t)NN * HDIM * 4));
    float* h3     = (float*)(ws + al((size_t)NN * 4));
    float* key    = (float*)(ws + al((size_t)NN * 4));
    int*   gcnt   = (int*)(ws + al((size_t)NG * 4));
    int*   gstart = (int*)(ws + al((size_t)(NG + 1) * 4));
    int*   sel    = (int*)(ws + al((size_t)NG * KTOP * 4));
    float* c1     = (float*)(ws + al((size_t)NG * 16 * KTOP * 4));
    unsigned short* S  = (unsigned short*)(ws + al((size_t)3 * NN * HDIM * 2));   // 61.4 MB split buf
    unsigned short* Wt = (unsigned short*)(ws + al((size_t)3 * 512 * 512 * 2));   // 1.6 MB
    float* x2 = (float*)S;   // aliases S (S dead after gemm2 reads it)
    (void)ws_size; (void)n_in; (void)out_size;

    int nb_n = (NN + 255) / 256;
    int nb_e = (NE + 255) / 256;

    k_init<<<nb_n, 256, 0, stream>>>(indeg, ccur, gcnt);
    k_count<<<nb_e, 256, 0, stream>>>(dstp, indeg, NE);
    k_gcount<<<nb_n, 256, 0, stream>>>(batch, gcnt);
    k_dinv<<<nb_n, 256, 0, stream>>>(indeg, dinv);
    k_scan<<<1, 256, 0, stream>>>(indeg, cstart, NN);
    k_scan<<<1, 256, 0, stream>>>(gcnt, gstart, NG);
    k_fill<<<nb_e, 256, 0, stream>>>(srcp, dstp, cstart, ccur, csrc, NE);

    const int n4 = NN * HDIM / 4;
    const int nsp = (n4 + 255) / 256;
    dim3 gw(16, 16);
    dim3 gg((NN + 63) / 64, 4);
    unsigned short* S1 = S + (size_t)NN * HDIM;
    unsigned short* S2 = S + (size_t)2 * NN * HDIM;

    // layer 1
    k_split<<<nsp, 256, 0, stream>>>(x, S, S1, S2, n4);
    k_splitW<<<gw, 256, 0, stream>>>(W1, Wt, Wt + 512 * 512, Wt + 2 * 512 * 512);
    k_gemm_mfma<<<gg, 256, 0, stream>>>(S, Wt, h, NN);
    k_agg<<<NN / 4, 256, 0, stream>>>(h, cstart, csrc, dinv, b1, nullptr, x1, S, S1, S2);  // fused split of x1
    // layer 2
    k_splitW<<<gw, 256, 0, stream>>>(W2, Wt, Wt + 512 * 512, Wt + 2 * 512 * 512);
    k_gemm_mfma<<<gg, 256, 0, stream>>>(S, Wt, h, NN);
    k_agg<<<NN / 4, 256, 0, stream>>>(h, cstart, csrc, dinv, b2, x1, x2, nullptr, nullptr, nullptr);
    // layer 3 + pool + head
    k_gemv3<<<NN / 4, 256, 0, stream>>>(x2, W3, h3);
    k_agg3<<<nb_n, 256, 0, stream>>>(h3, cstart, csrc, dinv, b3, key);
    k_select<<<NG, 256, 0, stream>>>(key, gstart, sel);
    k_conv1<<<NG * KTOP, 256, 0, stream>>>(x1, x2, key, sel, cw1, cb1, c1);
    k_head<<<NG, 512, 0, stream>>>(c1, cw2, cb2, lw1, lb1, lw2, lb2, (float*)d_out);
}